// Round 5
// baseline (809.900 us; speedup 1.0000x reference)
//
#include <hip/hip_runtime.h>
#include <stdint.h>

// RNN car-following, 256 sequential steps x 4096 vehicles.
// Round-5: ZERO-SYNC design. One wave (64 lanes) owns 8 vehicles for the whole
// rollout: conv1 -> conv2 -> dense -> state all in-wave. No __syncthreads, no
// cross-wave fences; LDS ordering is the wave's own in-order pipe (compiler
// lgkmcnt). Temporal-redundancy rings from R3/R4 kept (58 MFMA/step).
//  - old-slot P/O2 fragments prefetched BEFORE conv1's LDS writes (in-order
//    LDS pipe: later reads queue behind writes).
//  - dense2 TRANSPOSED (weights as A-operand -> D[o][veh]): reduction is
//    3 in-lane adds + shfl_xor(16,32) instead of 4-level butterfly x4.
//  - lead sample prefetched from global each step (no barrier -> no vmcnt
//    drain -> latency fully hidden); outputs stored direct, fire-and-forget.
// 512 WGs x 64 thr, 33.3 KB LDS, ~2 WG/CU.

#define PAST 25

typedef __attribute__((ext_vector_type(8))) short bf16x8;
typedef __attribute__((ext_vector_type(4))) float f32x4;
typedef unsigned short u16x2 __attribute__((ext_vector_type(2)));
#define MFMA16 __builtin_amdgcn_mfma_f32_16x16x32_bf16

static __device__ __forceinline__ uint32_t f2bf(float f) {
  union { float f; uint32_t u; } x; x.f = f;
  return (x.u + 0x7FFFu + ((x.u >> 16) & 1u)) >> 16;
}
static __device__ __forceinline__ float bf2f(uint32_t b) {
  union { uint32_t u; float f; } x; x.u = b << 16; return x.f;
}
static __device__ __forceinline__ uint32_t pkbf(float lo, float hi) {
  return f2bf(lo) | (f2bf(hi) << 16);
}
static __device__ __forceinline__ f32x4 bcast4(float v) { f32x4 r = {v, v, v, v}; return r; }

static __device__ __forceinline__ uint32_t pkmax(uint32_t a, uint32_t b) {
#if __has_builtin(__builtin_elementwise_max)
  union U { uint32_t w; u16x2 v; } x, y; x.w = a; y.w = b;
  x.v = __builtin_elementwise_max(x.v, y.v);
  return x.w;
#else
  uint32_t al = a << 16, bl = b << 16;
  uint32_t lo = (al > bl ? al : bl) >> 16;
  uint32_t ah = a & 0xffff0000u, bh = b & 0xffff0000u;
  uint32_t hi = ah > bh ? ah : bh;
  return lo | hi;
#endif
}
static __device__ __forceinline__ uint4 maxq(uint4 a, uint4 b) {
  uint4 r; r.x = pkmax(a.x, b.x); r.y = pkmax(a.y, b.y);
  r.z = pkmax(a.z, b.z); r.w = pkmax(a.w, b.w); return r;
}
static __device__ __forceinline__ int w21(int x) { if (x >= 21) x -= 21; if (x >= 21) x -= 21; return x; }
static __device__ __forceinline__ int w17(int x) { if (x >= 17) x -= 17; if (x >= 17) x -= 17; return x; }

union FragU { bf16x8 v; uint16_t u[8]; uint4 q; };
struct Acc4 { f32x4 a[4]; };

// 2112 + 11776 + 19456 = 33344 B
struct __align__(16) SMem {
  uint32_t Xcol[8][33][2];    // x-column ring (u&31): c0 = x0hi|x1<<16, c1 = x2|x0lo<<16
  uint16_t P[23 * 8 * 32];    // pooled conv1: ring 0..20 (g%21), 21=row0(padL), 22=row12(padR)
  uint16_t O2[19 * 8 * 64];   // out2: ring 0..16 (a%17), 17=j0, 18=j10
};

__global__ __launch_bounds__(64, 1) void rnncf_kernel(
    const float* __restrict__ lead_states, const float* __restrict__ cur_states,
    const float* __restrict__ conv1_w, const float* __restrict__ conv1_b,
    const float* __restrict__ conv2_w, const float* __restrict__ conv2_b,
    const float* __restrict__ dense2_w, const float* __restrict__ dense2_b,
    const float* __restrict__ dense1_w, const float* __restrict__ dense1_b,
    float* __restrict__ out, int nt, int ntw) {
  __shared__ SMem sm;
  const int lane = threadIdx.x;       // 0..63 (one wave)
  const int n = lane & 15;
  const int quad = lane >> 4;
  const int vbase = blockIdx.x * 8;

  // ---------------- init: Xcol ring u=0..24 ----------------
#pragma unroll
  for (int rep = 0; rep < 4; ++rep) {
    int idx = lane + 64 * rep;
    if (idx < 200) {
      int v = idx & 7, u = idx >> 3;
      const float2 l = *(const float2*)(lead_states + ((size_t)(vbase + v) * ntw + u) * 2);
      const float2 c = *(const float2*)(cur_states + ((size_t)(vbase + v) * PAST + u) * 2);
      float x0 = (l.x - c.x) * 0.005f;
      uint32_t hi = f2bf(x0);
      uint32_t lo = f2bf(x0 - bf2f(hi));
      sm.Xcol[v][u][0] = hi | (f2bf(c.y * 0.025f) << 16);
      sm.Xcol[v][u][1] = f2bf(l.y * 0.025f) | (lo << 16);
    }
  }
  // per-lane state (lanes 0..7 own vehicle = lane), scaled
  float pos_s = 0.f, spd_s = 0.f;
  if (lane < 8) {
    const float2 c = *(const float2*)(cur_states + ((size_t)(vbase + lane) * PAST + 24) * 2);
    pos_s = c.x * 0.005f; spd_s = c.y * 0.025f;
  }

  // ---------------- weight fragments ----------------
  // conv1: k = cig*4+dw (cig: x0hi, x1, x2, x0lo-dup)
  FragU B1[2];
#pragma unroll
  for (int ct = 0; ct < 2; ++ct)
#pragma unroll
    for (int jj = 0; jj < 8; ++jj) {
      int k = quad * 8 + jj;
      int dw = k & 3, cig = (k >> 2) & 3;
      float w = 0.f;
      if (k < 16 && dw < 3) {
        int ci = (cig == 3) ? 0 : cig;
        w = conv1_w[(dw * 3 + ci) * 32 + ct * 16 + n];
      }
      B1[ct].u[jj] = (uint16_t)f2bf(w);
    }
  // conv2: kappa -> ci = (kap&1)*16 + (kap>>1)
  FragU B2[3][4];
#pragma unroll
  for (int dw = 0; dw < 3; ++dw)
#pragma unroll
    for (int ct = 0; ct < 4; ++ct)
#pragma unroll
      for (int jj = 0; jj < 8; ++jj) {
        int kap = quad * 8 + jj;
        int ci = (kap & 1) * 16 + (kap >> 1);
        B2[dw][ct].u[jj] = (uint16_t)f2bf(conv2_w[(dw * 32 + ci) * 64 + ct * 16 + n]);
      }
  // dense2, used as A-operand (transposed): A[row=o=n][k]; same fragment data
  // as the old B-operand layout (identical (lane,reg)->(idx,k) map).
  FragU Bd[12];
#pragma unroll
  for (int kt = 0; kt < 12; ++kt)
#pragma unroll
    for (int jj = 0; jj < 8; ++jj) {
      int flat = kt * 32 + quad * 8 + jj;
      int jp = flat >> 6, kap = flat & 63;
      int co = (kap & 3) * 16 + (kap >> 2);
      Bd[kt].u[jj] = (uint16_t)f2bf((n < 10) ? dense2_w[(jp * 64 + co) * 10 + n] : 0.f);
    }
  const float b1v0 = conv1_b[n], b1v1 = conv1_b[16 + n];
  float b2v[4];
#pragma unroll
  for (int ct = 0; ct < 4; ++ct) b2v[ct] = conv2_b[ct * 16 + n];
  // dense bias / dense1 weight per accumulator ROW (o = quad*4+r)
  f32x4 dbias; float w1r[4];
#pragma unroll
  for (int r = 0; r < 4; ++r) {
    int o = quad * 4 + r;
    dbias[r] = (o < 10) ? dense2_b[o] : 0.f;
    w1r[r] = (o < 10) ? dense1_w[o] : 0.f;
  }
  const float bd1v = dense1_b[0];

  // ---------------- helpers ----------------
  auto pIdx = [&](int s, int veh, int ch) { return ((s * 8 + veh) * 4 + ch) * 8; };
  auto oIdx = [&](int s, int veh, int ch) { return ((s * 8 + veh) * 8 + ch) * 8; };

  auto build_x = [&](int c, int padL, int padR) -> FragU {
    int h = quad & 1, v8 = n & 7;
    uint32_t d0 = padL ? 0u : sm.Xcol[v8][(c - 1) & 31][h];
    uint32_t d1 = sm.Xcol[v8][c & 31][h];
    uint32_t d2 = padR ? 0u : sm.Xcol[v8][(c + 1) & 31][h];
    FragU a;
    a.q.x = __builtin_amdgcn_perm(d1, d0, 0x05040100u);
    a.q.y = d2 & 0xffffu;
    a.q.z = __builtin_amdgcn_perm(d1, d0, 0x07060302u);
    a.q.w = d2 >> 16;
    return a;
  };

  auto conv1_pair = [&](int cA, int pLA, int pRA, int cB, int pLB, int pRB, int ds) {
    FragU aA = build_x(cA, pLA, pRA);
    FragU aB = build_x(cB, pLB, pRB);
    f32x4 d0a = MFMA16(aA.v, B1[0].v, bcast4(b1v0), 0, 0, 0);
    f32x4 d0b = MFMA16(aB.v, B1[0].v, bcast4(b1v0), 0, 0, 0);
    f32x4 d1a = MFMA16(aA.v, B1[1].v, bcast4(b1v1), 0, 0, 0);
    f32x4 d1b = MFMA16(aB.v, B1[1].v, bcast4(b1v1), 0, 0, 0);
    if (quad < 2) {
#pragma unroll
      for (int r = 0; r < 4; ++r) {
        float e0 = fmaxf(fmaxf(d0a[r], d0b[r]), 0.f);
        float e1 = fmaxf(fmaxf(d1a[r], d1b[r]), 0.f);
        int veh = quad * 4 + r;
        *(uint32_t*)&sm.P[pIdx(ds, veh, (n >> 2) ^ (veh & 3)) + (n & 3) * 2] = pkbf(e0, e1);
      }
    }
  };

  auto conv1_single = [&](int c, int padL, int padR, int ds) {
    FragU a = build_x(c, padL, padR);
    f32x4 d0 = MFMA16(a.v, B1[0].v, bcast4(b1v0), 0, 0, 0);
    f32x4 d1 = MFMA16(a.v, B1[1].v, bcast4(b1v1), 0, 0, 0);
    if (quad < 2) {
#pragma unroll
      for (int r = 0; r < 4; ++r) {
        float e0 = fmaxf(d0[r], 0.f), e1 = fmaxf(d1[r], 0.f);
        int veh = quad * 4 + r;
        *(uint32_t*)&sm.P[pIdx(ds, veh, (n >> 2) ^ (veh & 3)) + (n & 3) * 2] = pkbf(e0, e1);
      }
    }
  };

  auto ld_P = [&](int s) -> FragU {
    FragU a; a.q = *(const uint4*)&sm.P[pIdx(s, n & 7, quad ^ (n & 3))]; return a;
  };

  auto c2init = [&]() -> Acc4 {
    Acc4 c;
#pragma unroll
    for (int ct = 0; ct < 4; ++ct) c.a[ct] = bcast4(b2v[ct]);
    return c;
  };
  auto c2acc = [&](Acc4& c, FragU a, int dw) {
#pragma unroll
    for (int ct = 0; ct < 4; ++ct) c.a[ct] = MFMA16(a.v, B2[dw][ct].v, c.a[ct], 0, 0, 0);
  };
  auto c2store = [&](Acc4& c, int ds) {
    if (quad < 2) {
#pragma unroll
      for (int r = 0; r < 4; ++r) {
        int veh = quad * 4 + r;
        float m0 = fmaxf(c.a[0][r], 0.f), m1 = fmaxf(c.a[1][r], 0.f);
        float m2 = fmaxf(c.a[2][r], 0.f), m3 = fmaxf(c.a[3][r], 0.f);
        uint2 w2; w2.x = pkbf(m0, m1); w2.y = pkbf(m2, m3);
        *(uint2*)&sm.O2[oIdx(ds, veh, (n >> 1) ^ (veh & 7)) + (n & 1) * 4] = w2;
      }
    }
  };

  auto ld_O = [&](int s, int hf) -> uint4 {
    return *(const uint4*)&sm.O2[oIdx(s, n & 7, (hf * 4 + quad) ^ (n & 7))];
  };
  auto ld_O_max = [&](int pa, int pb, int hf) -> FragU {
    FragU a;
    uint4 qa = ld_O(pa, hf);
    if (pb >= 0) qa = maxq(qa, ld_O(pb, hf));
    a.q = qa; return a;
  };

  // ---------------- ring init (single wave, in-order) ----------------
  for (int g = 2; g <= 21; ++g)
    conv1_pair(g, 0, 0, g + 1, 0, 0, g % 21);
  for (int a2 = 2; a2 <= 17; ++a2) {
    Acc4 c = c2init();
    c2acc(c, ld_P(a2 % 21), 0);
    c2acc(c, ld_P((a2 + 2) % 21), 1);
    c2acc(c, ld_P((a2 + 4) % 21), 2);
    c2store(c, a2 % 17);
  }

  // ---------------- sequential steps (zero barriers) ----------------
  int tm21 = 0, tm17 = 0;
  for (int t = 0; t < nt; ++t) {
    const int sP2 = w21(tm21 + 2), sP4 = w21(tm21 + 4);
    const int sP18 = w21(tm21 + 18), sP20 = w21(tm21 + 20), sP22 = w21(tm21 + 22);
    const int sO2 = w17(tm17 + 2), sO4 = w17(tm17 + 4), sO6 = w17(tm17 + 6);
    const int sO8 = w17(tm17 + 8), sO10 = w17(tm17 + 10), sO12 = w17(tm17 + 12);
    const int sO14 = w17(tm17 + 14), sO16 = w17(tm17 + 16), sO18 = w17(tm17 + 18);

    // A: early prefetches (issue before any LDS write this step)
    float2 lead_nxt; lead_nxt.x = 0.f; lead_nxt.y = 0.f;
    if (lane < 8) {
      int ui = t + PAST; if (ui > ntw - 1) ui = ntw - 1;
      lead_nxt = *(const float2*)(lead_states + ((size_t)(vbase + lane) * ntw + ui) * 2);
    }
    FragU pP2 = ld_P(sP2), pP4 = ld_P(sP4);          // conv2 old slots
    FragU pP18 = ld_P(sP18), pP20 = ld_P(sP20);
    FragU f1h0 = ld_O_max(sO4, sO6, 0), f1h1 = ld_O_max(sO4, sO6, 1);     // jp1
    FragU f2h0 = ld_O_max(sO8, sO10, 0), f2h1 = ld_O_max(sO8, sO10, 1);   // jp2
    FragU f3h0 = ld_O_max(sO12, sO14, 0), f3h1 = ld_O_max(sO12, sO14, 1); // jp3

    // B: fresh conv1 rows -> P (writes queue after A's reads: in-order pipe)
    conv1_pair(t, 1, 0, t + 1, 0, 0, 21);            // pool row 0 (left pad)
    conv1_pair(t + 22, 0, 0, t + 23, 0, 0, sP22);    // pool row 11 -> ring
    conv1_single(t + 24, 0, 1, 22);                  // pool row 12 (right pad)

    // C: dense old-part MFMAs (matrix pipe busy while P writes drain)
    f32x4 da0 = dbias, da1 = bcast4(0.f), da2 = bcast4(0.f), da3 = bcast4(0.f);
    da0 = MFMA16(Bd[2].v, f1h0.v, da0, 0, 0, 0);
    da1 = MFMA16(Bd[3].v, f1h1.v, da1, 0, 0, 0);
    da2 = MFMA16(Bd[4].v, f2h0.v, da2, 0, 0, 0);
    da3 = MFMA16(Bd[5].v, f2h1.v, da3, 0, 0, 0);
    da0 = MFMA16(Bd[6].v, f3h0.v, da0, 0, 0, 0);
    da1 = MFMA16(Bd[7].v, f3h1.v, da1, 0, 0, 0);

    // D: conv2 — old-term MFMAs from prefetched frags, then fresh
    Acc4 c0 = c2init(), c9 = c2init(), cA = c2init();
    c2acc(c0, pP2, 1); c2acc(c0, pP4, 2);            // j0 old terms
    c2acc(c9, pP18, 0); c2acc(c9, pP20, 1);          // j9 old terms
    c2acc(cA, pP20, 0);                              // j10 old term
    FragU p21 = ld_P(21), p22f = ld_P(sP22), p24 = ld_P(22);  // fresh reads
    c2acc(c0, p21, 0);  c2store(c0, 17);             // j0  -> local 17
    c2acc(c9, p22f, 2); c2store(c9, sO18);           // j9  -> ring
    c2acc(cA, p22f, 1); c2acc(cA, p24, 2); c2store(cA, 18);   // j10 -> local 18

    // E: dense fresh part (reads queue after D's writes)
    FragU g0h0 = ld_O_max(17, sO2, 0), g0h1 = ld_O_max(17, sO2, 1);       // jp0
    FragU g4h0 = ld_O_max(sO16, sO18, 0), g4h1 = ld_O_max(sO16, sO18, 1); // jp4
    FragU g5h0 = ld_O_max(18, -1, 0), g5h1 = ld_O_max(18, -1, 1);         // jp5
    da2 = MFMA16(Bd[0].v, g0h0.v, da2, 0, 0, 0);
    da3 = MFMA16(Bd[1].v, g0h1.v, da3, 0, 0, 0);
    da0 = MFMA16(Bd[8].v, g4h0.v, da0, 0, 0, 0);
    da1 = MFMA16(Bd[9].v, g4h1.v, da1, 0, 0, 0);
    da2 = MFMA16(Bd[10].v, g5h0.v, da2, 0, 0, 0);
    da3 = MFMA16(Bd[11].v, g5h1.v, da3, 0, 0, 0);

    // F: epilogue — D[o][veh]: col = n = vehicle, rows = o = quad*4+r
    f32x4 tot = (da0 + da1) + (da2 + da3);
    float p = fmaxf(tot[0], 0.f) * w1r[0] + fmaxf(tot[1], 0.f) * w1r[1] +
              fmaxf(tot[2], 0.f) * w1r[2] + fmaxf(tot[3], 0.f) * w1r[3];
    p += __shfl_xor(p, 16, 64);
    p += __shfl_xor(p, 32, 64);
    if (lane < 8) {
      float accv = 10.f * (p + bd1v) - 6.f;          // (MAXA-MINA)*x + MINA
      float np_s = pos_s + 0.02f * spd_s;            // scaled pos + DT*spd
      float nsp = spd_s * 40.f + 0.1f * accv;        // raw new speed
      pos_s = np_s; spd_s = nsp * 0.025f;
      float2 o2v; o2v.x = np_s * 200.f; o2v.y = nsp;
      *(float2*)(out + ((size_t)(vbase + lane) * nt + t) * 2) = o2v;
      // append x-column u = t+25
      float x0 = lead_nxt.x * 0.005f - np_s;
      uint32_t hi = f2bf(x0);
      uint32_t lo = f2bf(x0 - bf2f(hi));
      uint2 cc;
      cc.x = hi | (f2bf(spd_s) << 16);
      cc.y = f2bf(lead_nxt.y * 0.025f) | (lo << 16);
      *(uint2*)&sm.Xcol[lane][(t + PAST) & 31][0] = cc;
    }

    ++tm21; if (tm21 == 21) tm21 = 0;
    ++tm17; if (tm17 == 17) tm17 = 0;
  }
}

extern "C" void kernel_launch(void* const* d_in, const int* in_sizes, int n_in,
                              void* d_out, int out_size, void* d_ws, size_t ws_size,
                              hipStream_t stream) {
  const float* lead = (const float*)d_in[0];
  const float* cur  = (const float*)d_in[1];
  // d_in[2] = mask (unused by reference)
  const float* c1w = (const float*)d_in[3];
  const float* c1b = (const float*)d_in[4];
  const float* c2w = (const float*)d_in[5];
  const float* c2b = (const float*)d_in[6];
  const float* d2w = (const float*)d_in[7];
  const float* d2b = (const float*)d_in[8];
  const float* d1w = (const float*)d_in[9];
  const float* d1b = (const float*)d_in[10];
  float* out = (float*)d_out;

  int nveh = in_sizes[1] / (PAST * 2);   // 4096
  int ntw  = in_sizes[2] / nveh;         // nt + PAST - 1
  int nt   = ntw - PAST + 1;             // 256
  int nblocks = nveh / 8;                // 512 WGs x 1 wave

  rnncf_kernel<<<nblocks, 64, 0, stream>>>(lead, cur, c1w, c1b, c2w, c2b,
                                           d2w, d2b, d1w, d1b, out, nt, ntw);
}

// Round 6
// 574.093 us; speedup vs baseline: 1.4107x; 1.4107x over previous
//
#include <hip/hip_runtime.h>
#include <stdint.h>

// RNN car-following, 256 sequential steps x 4096 vehicles; 8 veh/WG, 512 WGs,
// 4 waves (256 thr), 2 WG/CU.
// Round-6: dependence-aware wave specialization, ONE barrier per step.
//   True serial chain (wave0, all in-wave): epilogue(t-1) -> col t+24 (shfl
//   broadcast, no LDS RT) -> conv1 rows 11/12 -> conv2 j9/j10 (old-row MFMA
//   terms precomputed by H3 last segment, passed as C-operands via LDS) ->
//   jp4/jp5 dense partials (kept in VGPRs across the barrier).
//   Helpers (segment t, consumed at t+1 across the barrier):
//     H1: r0 -> j0 -> jp0 partial      H2: jp1..jp3 partials (ring-only)
//     H3: j9/j10 old-term accs for step t+1 + lead prefetch -> LDS slot.
//   All cross-wave data crosses exactly one barrier (parity double-buffered).
//   wave0 stores outputs direct (issued early; vmcnt drain hidden); only H3
//   touches global loads.

#define PAST 25

typedef __attribute__((ext_vector_type(8))) short bf16x8;
typedef __attribute__((ext_vector_type(4))) float f32x4;
typedef unsigned short u16x2 __attribute__((ext_vector_type(2)));
#define MFMA16 __builtin_amdgcn_mfma_f32_16x16x32_bf16

static __device__ __forceinline__ uint32_t f2bf(float f) {
  union { float f; uint32_t u; } x; x.f = f;
  return (x.u + 0x7FFFu + ((x.u >> 16) & 1u)) >> 16;
}
static __device__ __forceinline__ float bf2f(uint32_t b) {
  union { uint32_t u; float f; } x; x.u = b << 16; return x.f;
}
static __device__ __forceinline__ uint32_t pkbf(float lo, float hi) {
  return f2bf(lo) | (f2bf(hi) << 16);
}
static __device__ __forceinline__ f32x4 bcast4(float v) { f32x4 r = {v, v, v, v}; return r; }

static __device__ __forceinline__ uint32_t pkmax(uint32_t a, uint32_t b) {
#if __has_builtin(__builtin_elementwise_max)
  union U { uint32_t w; u16x2 v; } x, y; x.w = a; y.w = b;
  x.v = __builtin_elementwise_max(x.v, y.v);
  return x.w;
#else
  uint32_t al = a << 16, bl = b << 16;
  uint32_t lo = (al > bl ? al : bl) >> 16;
  uint32_t ah = a & 0xffff0000u, bh = b & 0xffff0000u;
  uint32_t hi = ah > bh ? ah : bh;
  return lo | hi;
#endif
}
static __device__ __forceinline__ uint4 maxq(uint4 a, uint4 b) {
  uint4 r; r.x = pkmax(a.x, b.x); r.y = pkmax(a.y, b.y);
  r.z = pkmax(a.z, b.z); r.w = pkmax(a.w, b.w); return r;
}
static __device__ __forceinline__ int w21(int x) {
  if (x >= 21) x -= 21; if (x >= 21) x -= 21; if (x >= 21) x -= 21; return x;
}
static __device__ __forceinline__ int w17(int x) {
  if (x >= 17) x -= 17; if (x >= 17) x -= 17; if (x >= 17) x -= 17; return x;
}

union FragU { bf16x8 v; uint16_t u[8]; uint4 q; };
struct Acc4 { f32x4 a[4]; };

// 2112 + 11776 + 19456 + 4096 + 16384 + 128 = 53952 B (2 WG/CU: 108 KB < 160)
struct __align__(16) SMem {
  uint32_t Xcol[8][33][2];     // x-column ring (u&31); 33-pitch -> conflict-free
  uint16_t P[23 * 8 * 32];     // pooled conv1: ring 0..20 (g%21), 21=r0(H1), 22=r12(w0)
  uint16_t O2[19 * 8 * 64];    // out2: ring 0..16 (a%17), 17=j0(H1), 18=j10(w0)
  float jpacc[2][2][64][4];    // dense partials [par][H1|H2][lane] (f32x4)
  float accb[2][2][64][16];    // conv2 old-term C accs [par][j9|j10][lane][ct*4+r]
  float2 leadsl[2][8];         // lead sample handoff [par][veh]
};

__global__ __launch_bounds__(256, 2) void rnncf_kernel(
    const float* __restrict__ lead_states, const float* __restrict__ cur_states,
    const float* __restrict__ conv1_w, const float* __restrict__ conv1_b,
    const float* __restrict__ conv2_w, const float* __restrict__ conv2_b,
    const float* __restrict__ dense2_w, const float* __restrict__ dense2_b,
    const float* __restrict__ dense1_w, const float* __restrict__ dense1_b,
    float* __restrict__ out, int nt, int ntw) {
  __shared__ SMem sm;
  const int tid = threadIdx.x;
  const int lane = tid & 63;
  const int wid = tid >> 6;           // 0..3
  const int n = lane & 15;
  const int quad = lane >> 4;
  const int vbase = blockIdx.x * 8;

  // ---------------- init: Xcol u=0..24 ----------------
  if (tid < 200) {
    int v = tid & 7, u = tid >> 3;
    const float2 l = *(const float2*)(lead_states + ((size_t)(vbase + v) * ntw + u) * 2);
    const float2 c = *(const float2*)(cur_states + ((size_t)(vbase + v) * PAST + u) * 2);
    float x0 = (l.x - c.x) * 0.005f;
    uint32_t hi = f2bf(x0);
    uint32_t lo = f2bf(x0 - bf2f(hi));
    sm.Xcol[v][u][0] = hi | (f2bf(c.y * 0.025f) << 16);
    sm.Xcol[v][u][1] = f2bf(l.y * 0.025f) | (lo << 16);
  }
  float pos_s = 0.f, spd_s = 0.f;
  if (wid == 0 && lane < 8) {
    const float2 c = *(const float2*)(cur_states + ((size_t)(vbase + lane) * PAST + 24) * 2);
    pos_s = c.x * 0.005f; spd_s = c.y * 0.025f;
  }

  // ---------------- weight fragments (all waves load all) ----------------
  FragU B1[2];
#pragma unroll
  for (int ct = 0; ct < 2; ++ct)
#pragma unroll
    for (int jj = 0; jj < 8; ++jj) {
      int k = quad * 8 + jj;
      int dw = k & 3, cig = (k >> 2) & 3;
      float w = 0.f;
      if (k < 16 && dw < 3) {
        int ci = (cig == 3) ? 0 : cig;
        w = conv1_w[(dw * 3 + ci) * 32 + ct * 16 + n];
      }
      B1[ct].u[jj] = (uint16_t)f2bf(w);
    }
  FragU B2[3][4];
#pragma unroll
  for (int dw = 0; dw < 3; ++dw)
#pragma unroll
    for (int ct = 0; ct < 4; ++ct)
#pragma unroll
      for (int jj = 0; jj < 8; ++jj) {
        int kap = quad * 8 + jj;
        int ci = (kap & 1) * 16 + (kap >> 1);
        B2[dw][ct].u[jj] = (uint16_t)f2bf(conv2_w[(dw * 32 + ci) * 64 + ct * 16 + n]);
      }
  FragU Bd[12];
#pragma unroll
  for (int kt = 0; kt < 12; ++kt)
#pragma unroll
    for (int jj = 0; jj < 8; ++jj) {
      int flat = kt * 32 + quad * 8 + jj;
      int jp = flat >> 6, kap = flat & 63;
      int co = (kap & 3) * 16 + (kap >> 2);
      Bd[kt].u[jj] = (uint16_t)f2bf((n < 10) ? dense2_w[(jp * 64 + co) * 10 + n] : 0.f);
    }
  const float b1v0 = conv1_b[n], b1v1 = conv1_b[16 + n];
  float b2v[4];
#pragma unroll
  for (int ct = 0; ct < 4; ++ct) b2v[ct] = conv2_b[ct * 16 + n];
  f32x4 dbias; float w1r[4];
#pragma unroll
  for (int r = 0; r < 4; ++r) {
    int o = quad * 4 + r;
    dbias[r] = (o < 10) ? dense2_b[o] : 0.f;
    w1r[r] = (o < 10) ? dense1_w[o] : 0.f;
  }
  const float bd1v = dense1_b[0];

  // ---------------- helpers ----------------
  auto pIdx = [&](int s, int veh, int ch) { return ((s * 8 + veh) * 4 + ch) * 8; };
  auto oIdx = [&](int s, int veh, int ch) { return ((s * 8 + veh) * 8 + ch) * 8; };
  auto Xld = [&](int u) -> uint32_t { return sm.Xcol[n & 7][u & 31][quad & 1]; };

  auto mkfrag = [&](uint32_t d0, uint32_t d1, uint32_t d2) -> FragU {
    FragU a;
    a.q.x = __builtin_amdgcn_perm(d1, d0, 0x05040100u);
    a.q.y = d2 & 0xffffu;
    a.q.z = __builtin_amdgcn_perm(d1, d0, 0x07060302u);
    a.q.w = d2 >> 16;
    return a;
  };
  auto build_x = [&](int c, int padL, int padR) -> FragU {
    uint32_t d0 = padL ? 0u : Xld(c - 1);
    uint32_t d1 = Xld(c);
    uint32_t d2 = padR ? 0u : Xld(c + 1);
    return mkfrag(d0, d1, d2);
  };
  auto p_write = [&](int ds, float e0, float e1, int r) {
    int veh = quad * 4 + r;
    *(uint32_t*)&sm.P[pIdx(ds, veh, (n >> 2) ^ (veh & 3)) + (n & 3) * 2] = pkbf(e0, e1);
  };
  auto conv1_pair = [&](int cA, int pLA, int pRA, int cB, int pLB, int pRB, int ds) {
    FragU aA = build_x(cA, pLA, pRA);
    FragU aB = build_x(cB, pLB, pRB);
    f32x4 d0a = MFMA16(aA.v, B1[0].v, bcast4(b1v0), 0, 0, 0);
    f32x4 d0b = MFMA16(aB.v, B1[0].v, bcast4(b1v0), 0, 0, 0);
    f32x4 d1a = MFMA16(aA.v, B1[1].v, bcast4(b1v1), 0, 0, 0);
    f32x4 d1b = MFMA16(aB.v, B1[1].v, bcast4(b1v1), 0, 0, 0);
    if (quad < 2) {
#pragma unroll
      for (int r = 0; r < 4; ++r)
        p_write(ds, fmaxf(fmaxf(d0a[r], d0b[r]), 0.f), fmaxf(fmaxf(d1a[r], d1b[r]), 0.f), r);
    }
  };
  auto ld_P = [&](int s) -> FragU {
    FragU a; a.q = *(const uint4*)&sm.P[pIdx(s, n & 7, quad ^ (n & 3))]; return a;
  };
  auto c2init = [&]() -> Acc4 {
    Acc4 c;
#pragma unroll
    for (int ct = 0; ct < 4; ++ct) c.a[ct] = bcast4(b2v[ct]);
    return c;
  };
  auto c2acc = [&](Acc4& c, FragU a, int dw) {
#pragma unroll
    for (int ct = 0; ct < 4; ++ct) c.a[ct] = MFMA16(a.v, B2[dw][ct].v, c.a[ct], 0, 0, 0);
  };
  auto c2store = [&](Acc4& c, int ds) {
    if (quad < 2) {
#pragma unroll
      for (int r = 0; r < 4; ++r) {
        int veh = quad * 4 + r;
        float m0 = fmaxf(c.a[0][r], 0.f), m1 = fmaxf(c.a[1][r], 0.f);
        float m2 = fmaxf(c.a[2][r], 0.f), m3 = fmaxf(c.a[3][r], 0.f);
        uint2 w2; w2.x = pkbf(m0, m1); w2.y = pkbf(m2, m3);
        *(uint2*)&sm.O2[oIdx(ds, veh, (n >> 1) ^ (veh & 7)) + (n & 1) * 4] = w2;
      }
    }
  };
  auto ld_O = [&](int s, int hf) -> uint4 {
    return *(const uint4*)&sm.O2[oIdx(s, n & 7, (hf * 4 + quad) ^ (n & 7))];
  };
  auto ld_O_max = [&](int pa, int pb, int hf) -> FragU {
    FragU a;
    uint4 qa = ld_O(pa, hf);
    if (pb >= 0) qa = maxq(qa, ld_O(pb, hf));
    a.q = qa; return a;
  };

  __syncthreads();

  // ---------------- init phase 1: P ring g=2..21 (4 waves x 5) ----------------
#pragma unroll
  for (int i = 0; i < 5; ++i) {
    int g = 2 + wid + 4 * i;
    conv1_pair(g, 0, 0, g + 1, 0, 0, g % 21);
  }
  __syncthreads();

  // ---------------- init phase 2: O2 ring a=2..17 + prime accb[0] ----------------
#pragma unroll
  for (int i = 0; i < 4; ++i) {
    int a = 2 + wid + 4 * i;
    Acc4 c = c2init();
    c2acc(c, ld_P(a % 21), 0);
    c2acc(c, ld_P((a + 2) % 21), 1);
    c2acc(c, ld_P((a + 4) % 21), 2);
    c2store(c, a % 17);
  }
  if (wid == 3) {   // prime old-term accs for step 0 (sP18=g18, sP20=g20)
    FragU p18 = ld_P(18), p20 = ld_P(20);
    Acc4 c9o = c2init(); c2acc(c9o, p18, 0); c2acc(c9o, p20, 1);
    Acc4 cAo = c2init(); c2acc(cAo, p20, 0);
#pragma unroll
    for (int ct = 0; ct < 4; ++ct) {
      *(f32x4*)&sm.accb[0][0][lane][ct * 4] = c9o.a[ct];
      *(f32x4*)&sm.accb[0][1][lane][ct * 4] = cAo.a[ct];
    }
  }
  __syncthreads();

  // ---------------- segments t=0..nt (epilogue(t-1) + chain/helpers(t)) --------
  int tm21 = 0, tm17 = 0;
  f32x4 da45 = bcast4(0.f);
  for (int t = 0; t <= nt; ++t) {
    const int sP2 = w21(tm21 + 2), sP4 = w21(tm21 + 4), sP22 = w21(tm21 + 22);
    const int sO2 = w17(tm17 + 2), sO4 = w17(tm17 + 4), sO6 = w17(tm17 + 6);
    const int sO8 = w17(tm17 + 8), sO10 = w17(tm17 + 10), sO12 = w17(tm17 + 12);
    const int sO14 = w17(tm17 + 14), sO16 = w17(tm17 + 16), sO18 = w17(tm17 + 18);
    const int par = t & 1;

    if (wid == 0) {
      // ---- early issues ----
      f32x4 C9[4], CA[4]; uint4 q8h0, q8h1;
      uint32_t cA0 = 0, cA1 = 0, cA2 = 0;
      if (t < nt) {
#pragma unroll
        for (int ct = 0; ct < 4; ++ct) {
          C9[ct] = *(const f32x4*)&sm.accb[par][0][lane][ct * 4];
          CA[ct] = *(const f32x4*)&sm.accb[par][1][lane][ct * 4];
        }
        q8h0 = ld_O(sO16, 0); q8h1 = ld_O(sO16, 1);
        cA0 = Xld(t + 21); cA1 = Xld(t + 22); cA2 = Xld(t + 23);
      }
      // ---- epilogue(t-1) ----
      uint32_t ccx = 0, ccy = 0;
      if (t > 0) {
        int p1 = (t - 1) & 1;
        f32x4 jH1 = *(const f32x4*)&sm.jpacc[p1][0][lane][0];
        f32x4 jH3 = *(const f32x4*)&sm.jpacc[p1][1][lane][0];
        float2 ln = sm.leadsl[p1][lane & 7];
        f32x4 tot = da45 + jH1 + jH3;
        float p = fmaxf(tot[0], 0.f) * w1r[0] + fmaxf(tot[1], 0.f) * w1r[1] +
                  fmaxf(tot[2], 0.f) * w1r[2] + fmaxf(tot[3], 0.f) * w1r[3];
        p += __shfl_xor(p, 16, 64);
        p += __shfl_xor(p, 32, 64);
        if (lane < 8) {
          float accv = 10.f * (p + bd1v) - 6.f;        // (MAXA-MINA)*x + MINA
          float np_s = pos_s + 0.02f * spd_s;
          float nsp = spd_s * 40.f + 0.1f * accv;
          pos_s = np_s; spd_s = nsp * 0.025f;
          float2 o2v; o2v.x = np_s * 200.f; o2v.y = nsp;
          *(float2*)(out + ((size_t)(vbase + lane) * nt + (t - 1)) * 2) = o2v;
          float x0 = ln.x * 0.005f - np_s;             // column u = (t-1)+25 = t+24
          uint32_t hi = f2bf(x0);
          uint32_t lo = f2bf(x0 - bf2f(hi));
          ccx = hi | (f2bf(spd_s) << 16);
          ccy = f2bf(ln.y * 0.025f) | (lo << 16);
          uint2 cc; cc.x = ccx; cc.y = ccy;
          *(uint2*)&sm.Xcol[lane][(t + 24) & 31][0] = cc;
        }
      }
      // ---- chain(t) ----
      if (t < nt) {
        uint32_t colnew;
        if (t == 0) colnew = Xld(24);
        else {
          uint32_t sx = (uint32_t)__shfl((int)ccx, n & 7, 64);
          uint32_t sy = (uint32_t)__shfl((int)ccy, n & 7, 64);
          colnew = (quad & 1) ? sy : sx;
        }
        // conv1 rows 11 (centers t+22,t+23) and 12 (center t+24)
        FragU aA = mkfrag(cA0, cA1, cA2);
        FragU aB = mkfrag(cA1, cA2, colnew);
        FragU aC = mkfrag(cA2, colnew, 0u);
        f32x4 d0a = MFMA16(aA.v, B1[0].v, bcast4(b1v0), 0, 0, 0);
        f32x4 d0b = MFMA16(aB.v, B1[0].v, bcast4(b1v0), 0, 0, 0);
        f32x4 d1a = MFMA16(aA.v, B1[1].v, bcast4(b1v1), 0, 0, 0);
        f32x4 d1b = MFMA16(aB.v, B1[1].v, bcast4(b1v1), 0, 0, 0);
        f32x4 e0 = MFMA16(aC.v, B1[0].v, bcast4(b1v0), 0, 0, 0);
        f32x4 e1 = MFMA16(aC.v, B1[1].v, bcast4(b1v1), 0, 0, 0);
        if (quad < 2) {
#pragma unroll
          for (int r = 0; r < 4; ++r) {
            p_write(sP22, fmaxf(fmaxf(d0a[r], d0b[r]), 0.f),
                    fmaxf(fmaxf(d1a[r], d1b[r]), 0.f), r);
            p_write(22, fmaxf(e0[r], 0.f), fmaxf(e1[r], 0.f), r);
          }
        }
        FragU fr11 = ld_P(sP22);
        FragU fr12 = ld_P(22);
        // j9 = old(c9) + r11*dw2 -> ring sO18
        Acc4 c9;
#pragma unroll
        for (int ct = 0; ct < 4; ++ct)
          c9.a[ct] = MFMA16(fr11.v, B2[2][ct].v, C9[ct], 0, 0, 0);
        c2store(c9, sO18);
        // j10 = old(cA) + r11*dw1 + r12*dw2 -> local 18
        Acc4 cAa;
#pragma unroll
        for (int ct = 0; ct < 4; ++ct) {
          f32x4 x = MFMA16(fr11.v, B2[1][ct].v, CA[ct], 0, 0, 0);
          cAa.a[ct] = MFMA16(fr12.v, B2[2][ct].v, x, 0, 0, 0);
        }
        c2store(cAa, 18);
        // jp4 = max(j8, j9); jp5 = j10  -> da45 (VGPR carry)
        FragU j4h0, j4h1, j5h0, j5h1;
        j4h0.q = maxq(q8h0, ld_O(sO18, 0));
        j4h1.q = maxq(q8h1, ld_O(sO18, 1));
        j5h0.q = ld_O(18, 0);
        j5h1.q = ld_O(18, 1);
        f32x4 za = bcast4(0.f), zb = bcast4(0.f);
        za = MFMA16(Bd[8].v, j4h0.v, za, 0, 0, 0);
        zb = MFMA16(Bd[9].v, j4h1.v, zb, 0, 0, 0);
        za = MFMA16(Bd[10].v, j5h0.v, za, 0, 0, 0);
        zb = MFMA16(Bd[11].v, j5h1.v, zb, 0, 0, 0);
        da45 = za + zb;
      }
    } else if (wid == 1 && t < nt) {
      // ---- H1: r0 -> j0 -> jp0 partial ----
      conv1_pair(t, 1, 0, t + 1, 0, 0, 21);
      FragU a0 = ld_P(21), a2 = ld_P(sP2), a4 = ld_P(sP4);
      Acc4 c = c2init();
      c2acc(c, a0, 0); c2acc(c, a2, 1); c2acc(c, a4, 2);
      c2store(c, 17);
      FragU h0 = ld_O_max(17, sO2, 0), h1 = ld_O_max(17, sO2, 1);
      f32x4 p0 = dbias, p1v = bcast4(0.f);
      p0 = MFMA16(Bd[0].v, h0.v, p0, 0, 0, 0);
      p1v = MFMA16(Bd[1].v, h1.v, p1v, 0, 0, 0);
      *(f32x4*)&sm.jpacc[par][0][lane][0] = p0 + p1v;
    } else if (wid == 2 && t < nt) {
      // ---- H2: jp1..jp3 partials (ring-only) ----
      f32x4 q0 = bcast4(0.f), q1 = bcast4(0.f);
      FragU h;
      h = ld_O_max(sO4, sO6, 0);  q0 = MFMA16(Bd[2].v, h.v, q0, 0, 0, 0);
      h = ld_O_max(sO4, sO6, 1);  q1 = MFMA16(Bd[3].v, h.v, q1, 0, 0, 0);
      h = ld_O_max(sO8, sO10, 0); q0 = MFMA16(Bd[4].v, h.v, q0, 0, 0, 0);
      h = ld_O_max(sO8, sO10, 1); q1 = MFMA16(Bd[5].v, h.v, q1, 0, 0, 0);
      h = ld_O_max(sO12, sO14, 0); q0 = MFMA16(Bd[6].v, h.v, q0, 0, 0, 0);
      h = ld_O_max(sO12, sO14, 1); q1 = MFMA16(Bd[7].v, h.v, q1, 0, 0, 0);
      *(f32x4*)&sm.jpacc[par][1][lane][0] = q0 + q1;
    } else if (wid == 3 && t < nt) {
      // ---- H3: old-term accs for step t+1 + lead prefetch for epilogue(t) ----
      FragU p19 = ld_P(w21(tm21 + 19)), p21 = ld_P(w21(tm21 + 21));
      Acc4 c9o = c2init(); c2acc(c9o, p19, 0); c2acc(c9o, p21, 1);
      Acc4 cAo = c2init(); c2acc(cAo, p21, 0);
      int parn = (t + 1) & 1;
#pragma unroll
      for (int ct = 0; ct < 4; ++ct) {
        *(f32x4*)&sm.accb[parn][0][lane][ct * 4] = c9o.a[ct];
        *(f32x4*)&sm.accb[parn][1][lane][ct * 4] = cAo.a[ct];
      }
      if (lane < 8) {
        int ui = t + PAST; if (ui > ntw - 1) ui = ntw - 1;
        float2 l = *(const float2*)(lead_states + ((size_t)(vbase + lane) * ntw + ui) * 2);
        sm.leadsl[par][lane] = l;
      }
    }
    __syncthreads();

    ++tm21; if (tm21 == 21) tm21 = 0;
    ++tm17; if (tm17 == 17) tm17 = 0;
  }
}

extern "C" void kernel_launch(void* const* d_in, const int* in_sizes, int n_in,
                              void* d_out, int out_size, void* d_ws, size_t ws_size,
                              hipStream_t stream) {
  const float* lead = (const float*)d_in[0];
  const float* cur  = (const float*)d_in[1];
  // d_in[2] = mask (unused by reference)
  const float* c1w = (const float*)d_in[3];
  const float* c1b = (const float*)d_in[4];
  const float* c2w = (const float*)d_in[5];
  const float* c2b = (const float*)d_in[6];
  const float* d2w = (const float*)d_in[7];
  const float* d2b = (const float*)d_in[8];
  const float* d1w = (const float*)d_in[9];
  const float* d1b = (const float*)d_in[10];
  float* out = (float*)d_out;

  int nveh = in_sizes[1] / (PAST * 2);   // 4096
  int ntw  = in_sizes[2] / nveh;         // nt + PAST - 1
  int nt   = ntw - PAST + 1;             // 256
  int nblocks = nveh / 8;                // 512 WGs x 4 waves

  rnncf_kernel<<<nblocks, 256, 0, stream>>>(lead, cur, c1w, c1b, c2w, c2b,
                                            d2w, d2b, d1w, d1b, out, nt, ntw);
}